// Round 3
// baseline (38.430 us; speedup 1.0000x reference)
//
#include <hip/hip_runtime.h>
#include <math.h>

#define BB 32
#define TT 200
#define NCC 10
#define FF 2048
#define KK 3
#define NBLK (2 * NCC * BB * 2)   // 1280 blocks: (side, nc, b, f-half)

// Butterfly argmax across a 64-lane wave: max value, ties -> lower index.
// Matches jax.lax.top_k (descending, stable) — verified passing in R1/R2.
__device__ inline void wave_argmax(float& v, int& i) {
    #pragma unroll
    for (int m = 1; m < 64; m <<= 1) {
        float ov = __shfl_xor(v, m);
        int   oi = __shfl_xor(i, m);
        if (ov > v || (ov == v && oi < i)) { v = ov; i = oi; }
    }
}

__device__ inline float wave_sum(float v) {
    #pragma unroll
    for (int m = 1; m < 64; m <<= 1) v += __shfl_xor(v, m);
    return v;
}

// ---------------------------------------------------------------------------
// One fused kernel. blk = ((side*NCC + nc)*BB + b)*2 + fc.
// Every wave redundantly computes the masked top-3 for (side,b) in registers;
// each thread gathers one float4 from each of the 3 selected rows of its
// F-half, block-reduces sum-of-squares of the row-sum (scaled by 1/3 later),
// and the LAST block (atomic counter) composes the two output scalars.
// ---------------------------------------------------------------------------
__global__ __launch_bounds__(256) void fused_kernel(
        const float* __restrict__ abnr_magn,
        const float* __restrict__ norm_magn,
        const float* __restrict__ abnr_feats,
        const float* __restrict__ norm_feats,
        const float* __restrict__ abnr_sls,
        const float* __restrict__ norm_sls,
        const float* __restrict__ abnr_u,
        const float* __restrict__ norm_u,
        float* __restrict__ partial /* [NBLK]  raw sum((a0+a1+a2)^2) */,
        float* __restrict__ bce     /* [2*BB]  per-(side,b) log term */,
        int*   __restrict__ counter,
        float* __restrict__ out) {
    const int blk  = blockIdx.x;
    const int fc   = blk & 1;
    const int r    = blk >> 1;         // (side*NCC + nc)*BB + b
    const int b    = r % BB;
    const int sn   = r / BB;
    const int side = sn / NCC;
    const int nc   = sn % NCC;
    const int tid  = threadIdx.x;
    const int lane = tid & 63;
    const int wav  = tid >> 6;

    const float* magn  = side ? norm_magn  : abnr_magn;
    const float* u     = side ? norm_u     : abnr_u;
    const float* feats = side ? norm_feats : abnr_feats;

    // ---- masked top-3, computed redundantly per wave (all cached loads) ----
    const float scale = 1.0f / (1.0f - 0.7f);
    float vv[4];
    int   tv[4];
    #pragma unroll
    for (int j = 0; j < 4; ++j) {
        int t = lane + 64 * j;
        if (t < TT) {
            float m = (u[b * TT + t] >= 0.7f) ? scale : 0.0f;
            vv[j] = magn[b * TT + t] * m;
            tv[j] = t;
        } else {
            vv[j] = -INFINITY;
            tv[j] = 1 << 30;
        }
    }
    int id[KK];
    #pragma unroll
    for (int k = 0; k < KK; ++k) {
        float bv = -INFINITY;
        int   bi = 1 << 30;
        #pragma unroll
        for (int j = 0; j < 4; ++j)
            if (vv[j] > bv || (vv[j] == bv && tv[j] < bi)) { bv = vv[j]; bi = tv[j]; }
        wave_argmax(bv, bi);
        id[k] = bi;
        #pragma unroll
        for (int j = 0; j < 4; ++j)
            if (tv[j] == bi) vv[j] = -INFINITY;
    }

    // ---- gather: one float4 per thread from each of 3 rows of this F-half ----
    const size_t base = (size_t)(nc * BB + b) * (TT * FF) + (size_t)fc * (FF / 2) + tid * 4;
    float4 x0 = *(const float4*)(feats + base + (size_t)id[0] * FF);
    float4 x1 = *(const float4*)(feats + base + (size_t)id[1] * FF);
    float4 x2 = *(const float4*)(feats + base + (size_t)id[2] * FF);
    float m0 = x0.x + x1.x + x2.x;
    float m1 = x0.y + x1.y + x2.y;
    float m2 = x0.z + x1.z + x2.z;
    float m3 = x0.w + x1.w + x2.w;
    float acc = m0 * m0 + m1 * m1 + m2 * m2 + m3 * m3;

    acc = wave_sum(acc);

    __shared__ float s_red[4];
    __shared__ float s_redA[4];
    __shared__ float s_redB[4];
    __shared__ int   s_flag;
    if (lane == 0) s_red[wav] = acc;
    __syncthreads();

    if (tid == 0) {
        float tot = s_red[0] + s_red[1] + s_red[2] + s_red[3];
        __hip_atomic_store(&partial[blk], tot, __ATOMIC_RELAXED, __HIP_MEMORY_SCOPE_AGENT);
        if (nc == 0 && fc == 0) {
            const float* sls = side ? norm_sls : abnr_sls;
            float v = (sls[b * TT + id[0]] + sls[b * TT + id[1]] + sls[b * TT + id[2]]) *
                      (1.0f / 3.0f);
            float term = side ? fmaxf(logf(1.0f - v), -100.0f)
                              : fmaxf(logf(v), -100.0f);
            __hip_atomic_store(&bce[side * BB + b], term, __ATOMIC_RELAXED,
                               __HIP_MEMORY_SCOPE_AGENT);
        }
        int old = __hip_atomic_fetch_add(counter, 1, __ATOMIC_ACQ_REL,
                                         __HIP_MEMORY_SCOPE_AGENT);
        s_flag = (old == NBLK - 1);
    }
    __syncthreads();
    if (!s_flag) return;

    // ---- last block: compose the two scalars (deterministic, fixed order) ----
    const float third = 1.0f / 3.0f;
    float s = 0.0f;
    for (int i = tid; i < NCC * BB; i += 256) {
        float pa = __hip_atomic_load(&partial[2 * i], __ATOMIC_RELAXED, __HIP_MEMORY_SCOPE_AGENT)
                 + __hip_atomic_load(&partial[2 * i + 1], __ATOMIC_RELAXED, __HIP_MEMORY_SCOPE_AGENT);
        float pn = __hip_atomic_load(&partial[2 * (NCC * BB + i)], __ATOMIC_RELAXED, __HIP_MEMORY_SCOPE_AGENT)
                 + __hip_atomic_load(&partial[2 * (NCC * BB + i) + 1], __ATOMIC_RELAXED, __HIP_MEMORY_SCOPE_AGENT);
        float l2a = sqrtf(pa) * third;  // sqrt(sum((a0+a1+a2)^2)) / 3 == ||mean||
        float l2n = sqrtf(pn) * third;
        float t = fabsf(100.0f - l2a) + l2n;
        s += t * t;
    }
    s = wave_sum(s);
    if (lane == 0) s_redA[wav] = s;

    float s2 = 0.0f;
    if (tid < 2 * BB)
        s2 = __hip_atomic_load(&bce[tid], __ATOMIC_RELAXED, __HIP_MEMORY_SCOPE_AGENT);
    s2 = wave_sum(s2);
    if (lane == 0) s_redB[wav] = s2;
    __syncthreads();

    if (tid == 0) {
        float loss_rtfm = (s_redA[0] + s_redA[1] + s_redA[2] + s_redA[3]) *
                          (1.0f / (float)(NCC * BB));
        float bsum = s_redB[0] + s_redB[1] + s_redB[2] + s_redB[3];
        out[0] = 1e-4f * loss_rtfm;
        out[1] = -bsum * (1.0f / (float)BB);
    }
}

extern "C" void kernel_launch(void* const* d_in, const int* in_sizes, int n_in,
                              void* d_out, int out_size, void* d_ws, size_t ws_size,
                              hipStream_t stream) {
    const float* abnr_magn  = (const float*)d_in[0];
    const float* norm_magn  = (const float*)d_in[1];
    const float* abnr_feats = (const float*)d_in[2];
    const float* norm_feats = (const float*)d_in[3];
    const float* abnr_sls   = (const float*)d_in[4];
    const float* norm_sls   = (const float*)d_in[5];
    const float* abnr_u     = (const float*)d_in[6];
    const float* norm_u     = (const float*)d_in[7];
    float* out = (float*)d_out;

    int*   counter = (int*)d_ws;                          // 4 B
    float* bce     = (float*)((char*)d_ws + 256);         // 64 floats
    float* partial = (float*)((char*)d_ws + 4096);        // 1280 floats

    hipMemsetAsync(counter, 0, sizeof(int), stream);      // capturable memset node

    fused_kernel<<<NBLK, 256, 0, stream>>>(abnr_magn, norm_magn,
                                           abnr_feats, norm_feats,
                                           abnr_sls, norm_sls,
                                           abnr_u, norm_u,
                                           partial, bce, counter, out);
}

// Round 4
// 11.890 us; speedup vs baseline: 3.2322x; 3.2322x over previous
//
#include <hip/hip_runtime.h>
#include <math.h>

#define BB 32
#define TT 200
#define NCC 10
#define FF 2048
#define KK 3
#define NBLK (2 * NCC * BB * 2)   // 1280 = (side, nc, b, f-half); 5 blocks/CU exactly

// Butterfly argmax across a 64-lane wave: max value, ties -> lower index.
// Matches jax.lax.top_k (descending, stable) — verified passing in R1/R2.
__device__ inline void wave_argmax(float& v, int& i) {
    #pragma unroll
    for (int m = 1; m < 64; m <<= 1) {
        float ov = __shfl_xor(v, m);
        int   oi = __shfl_xor(i, m);
        if (ov > v || (ov == v && oi < i)) { v = ov; i = oi; }
    }
}

__device__ inline float wave_sum(float v) {
    #pragma unroll
    for (int m = 1; m < 64; m <<= 1) v += __shfl_xor(v, m);
    return v;
}

// ---------------------------------------------------------------------------
// Fused kernel. blk = ((side*NCC + nc)*BB + b)*2 + fc.
// Wave 0 computes the masked top-3 for (side, b) and broadcasts via LDS;
// all 256 threads gather one float4 from each of the 3 selected half-rows,
// block-reduce sum((a0+a1+a2)^2) -> partial[blk]. nc==0 && fc==0 blocks also
// emit the per-(side,b) BCE log term.
// ---------------------------------------------------------------------------
__global__ __launch_bounds__(256) void fused_kernel(
        const float* __restrict__ abnr_magn,
        const float* __restrict__ norm_magn,
        const float* __restrict__ abnr_feats,
        const float* __restrict__ norm_feats,
        const float* __restrict__ abnr_sls,
        const float* __restrict__ norm_sls,
        const float* __restrict__ abnr_u,
        const float* __restrict__ norm_u,
        float* __restrict__ partial /* [NBLK] */,
        float* __restrict__ bce     /* [2*BB] */) {
    const int blk  = blockIdx.x;
    const int fc   = blk & 1;
    const int r    = blk >> 1;         // (side*NCC + nc)*BB + b
    const int b    = r % BB;
    const int sn   = r / BB;
    const int side = sn / NCC;
    const int nc   = sn % NCC;
    const int tid  = threadIdx.x;
    const int lane = tid & 63;
    const int wav  = tid >> 6;

    const float* feats = side ? norm_feats : abnr_feats;

    __shared__ int   s_idx[KK];
    __shared__ float s_red[4];

    int id0, id1, id2;

    // ---- masked top-3 on wave 0 only (loads hit L2; ~1.6 KB per row) ----
    if (wav == 0) {
        const float* magn = side ? norm_magn : abnr_magn;
        const float* u    = side ? norm_u    : abnr_u;
        const float scale = 1.0f / (1.0f - 0.7f);
        float vv[4];
        int   tv[4];
        #pragma unroll
        for (int j = 0; j < 4; ++j) {
            int t = lane + 64 * j;
            if (t < TT) {
                float m = (u[b * TT + t] >= 0.7f) ? scale : 0.0f;
                vv[j] = magn[b * TT + t] * m;
                tv[j] = t;
            } else {
                vv[j] = -INFINITY;
                tv[j] = 1 << 30;
            }
        }
        int id[KK];
        #pragma unroll
        for (int k = 0; k < KK; ++k) {
            float bv = -INFINITY;
            int   bi = 1 << 30;
            #pragma unroll
            for (int j = 0; j < 4; ++j)
                if (vv[j] > bv || (vv[j] == bv && tv[j] < bi)) { bv = vv[j]; bi = tv[j]; }
            wave_argmax(bv, bi);
            id[k] = bi;
            #pragma unroll
            for (int j = 0; j < 4; ++j)
                if (tv[j] == bi) vv[j] = -INFINITY;
        }
        if (lane < KK) s_idx[lane] = id[lane];

        // BCE term for this (side, b): once per side/b (nc==0, fc==0 block).
        if (nc == 0 && fc == 0 && lane == 0) {
            const float* sls = side ? norm_sls : abnr_sls;
            float v = (sls[b * TT + id[0]] + sls[b * TT + id[1]] +
                       sls[b * TT + id[2]]) * (1.0f / 3.0f);
            bce[side * BB + b] = side ? fmaxf(logf(1.0f - v), -100.0f)
                                      : fmaxf(logf(v), -100.0f);
        }
    }
    __syncthreads();
    id0 = s_idx[0]; id1 = s_idx[1]; id2 = s_idx[2];

    // ---- gather: one float4 per thread from each of 3 half-rows ----
    const size_t base = (size_t)(nc * BB + b) * (TT * FF) + (size_t)fc * (FF / 2) + tid * 4;
    float4 x0 = *(const float4*)(feats + base + (size_t)id0 * FF);
    float4 x1 = *(const float4*)(feats + base + (size_t)id1 * FF);
    float4 x2 = *(const float4*)(feats + base + (size_t)id2 * FF);
    float m0 = x0.x + x1.x + x2.x;
    float m1 = x0.y + x1.y + x2.y;
    float m2 = x0.z + x1.z + x2.z;
    float m3 = x0.w + x1.w + x2.w;
    float acc = m0 * m0 + m1 * m1 + m2 * m2 + m3 * m3;

    acc = wave_sum(acc);
    if (lane == 0) s_red[wav] = acc;
    __syncthreads();
    if (tid == 0)
        partial[blk] = s_red[0] + s_red[1] + s_red[2] + s_red[3];
}

// ---------------------------------------------------------------------------
// Final: compose the two output scalars from 1280 partials + 64 BCE terms.
// Deterministic fixed-order reduction, single block.
// ---------------------------------------------------------------------------
__global__ __launch_bounds__(256) void final_kernel(
        const float* __restrict__ partial, const float* __restrict__ bce,
        float* __restrict__ out) {
    __shared__ float sA[4], sB[4];
    const int tid  = threadIdx.x;
    const int lane = tid & 63;
    const int wav  = tid >> 6;
    const float third = 1.0f / 3.0f;

    float s = 0.0f;
    for (int i = tid; i < NCC * BB; i += 256) {
        float pa = partial[2 * i] + partial[2 * i + 1];
        float pn = partial[2 * (NCC * BB + i)] + partial[2 * (NCC * BB + i) + 1];
        float l2a = sqrtf(pa) * third;   // ||mean over K|| = sqrt(sum((Σrows)^2))/3
        float l2n = sqrtf(pn) * third;
        float t = fabsf(100.0f - l2a) + l2n;
        s += t * t;
    }
    s = wave_sum(s);
    if (lane == 0) sA[wav] = s;

    float s2 = (tid < 2 * BB) ? bce[tid] : 0.0f;
    s2 = wave_sum(s2);
    if (lane == 0) sB[wav] = s2;
    __syncthreads();

    if (tid == 0) {
        float loss_rtfm = (sA[0] + sA[1] + sA[2] + sA[3]) * (1.0f / (float)(NCC * BB));
        float bsum = sB[0] + sB[1] + sB[2] + sB[3];
        out[0] = 1e-4f * loss_rtfm;
        out[1] = -bsum * (1.0f / (float)BB);
    }
}

extern "C" void kernel_launch(void* const* d_in, const int* in_sizes, int n_in,
                              void* d_out, int out_size, void* d_ws, size_t ws_size,
                              hipStream_t stream) {
    const float* abnr_magn  = (const float*)d_in[0];
    const float* norm_magn  = (const float*)d_in[1];
    const float* abnr_feats = (const float*)d_in[2];
    const float* norm_feats = (const float*)d_in[3];
    const float* abnr_sls   = (const float*)d_in[4];
    const float* norm_sls   = (const float*)d_in[5];
    const float* abnr_u     = (const float*)d_in[6];
    const float* norm_u     = (const float*)d_in[7];
    float* out = (float*)d_out;

    float* bce     = (float*)d_ws;                        // 64 floats
    float* partial = (float*)((char*)d_ws + 4096);        // 1280 floats

    fused_kernel<<<NBLK, 256, 0, stream>>>(abnr_magn, norm_magn,
                                           abnr_feats, norm_feats,
                                           abnr_sls, norm_sls,
                                           abnr_u, norm_u,
                                           partial, bce);
    final_kernel<<<1, 256, 0, stream>>>(partial, bce, out);
}